// Round 10
// baseline (2504.340 us; speedup 1.0000x reference)
//
#include <hip/hip_runtime.h>

// VQ nearest-codebook: N=262144 rows x D=64, K=1024 codes.
// Numerics contract (bit-exact vs np f32 reference, verified in prior session):
//   dist_k = fl32( fl32(zsq - 2*dot_k) + cbsq_k ), argmin -> lowest index wins.
//   dot_k MUST be one sequential fmaf chain d=0..63 per row. DO NOT re-associate.
//   zsq/cbsq: f64-accumulate then round once. (2*s exact; contraction of
//   zsq-2*s to fma(-2,s,zsq) is value-identical.)
//
// R13 change: leave the SMEM pipe. R=4 rows/thread, all-VECTOR codebook,
//   double-buffered in VGPRs, 1 wave/SIMD.
//   Diagnosis (R12): wall/row = 1220 cyc = 2 x L_smem (L~615). The two
//   lgkmcnt(0) drain-alls per row ARE the kernel; issue time hides between
//   them (wall = 2L exactly). SMEM = out-of-order return = drain-all; no
//   deeper SGPR pipeline fits the ~102-SGPR file. Vector loads use vmcnt =
//   COUNTED, in-order -> double-buffer pipelines with zero forced sync.
//   Vector cost = RF-writeback replication: waves x 16 loads x 8cyc/row/CU.
//   At R=2 (8 waves) = 1024 cyc (the R4/R6 wall). At R=4 -> 4 waves/CU,
//   1 wave/SIMD: writeback 512 ~ issue 590 -> balanced, no drains.
//   VGPR: q 4x16 float4 = 256 + U/W bufs 128 + temps ~40 = ~425 < 512
//   (waves_per_eu(1,1) grants the full file at 1 wave/SIMD).
//   Grid = N/1024 = 256 blocks = exactly 1 block/CU. Plain (non-AS4)
//   pointers keep the loads VECTOR (R4/R6/R11 behavior); reissue placed
//   after last read of the buffer (WAR-ordered by regalloc), distance to
//   next use ~1 row ~580 cyc >= L2 latency.
//   Gates: VGPR_Count >= ~380; WRITE ~68MB (>>70 = spill -> revert).
//   NO per-thread arrays anywhere (scratch hazard) -- all named values.

#define VQ_D 64
#define VQ_MAXK 1024

// 4-row sequential fused-FMA chain step over one float4-worth of c (ascending
// d within each row's chain; the 4 chains are independent -> ILP without
// reassociation).
#define VQ_CH4(pa, pb, pc, pd, c) do { \
    s0 = fmaf((pa).x, (c).x, s0); s1 = fmaf((pb).x, (c).x, s1); \
    s2 = fmaf((pc).x, (c).x, s2); s3 = fmaf((pd).x, (c).x, s3); \
    s0 = fmaf((pa).y, (c).y, s0); s1 = fmaf((pb).y, (c).y, s1); \
    s2 = fmaf((pc).y, (c).y, s2); s3 = fmaf((pd).y, (c).y, s3); \
    s0 = fmaf((pa).z, (c).z, s0); s1 = fmaf((pb).z, (c).z, s1); \
    s2 = fmaf((pc).z, (c).z, s2); s3 = fmaf((pd).z, (c).z, s3); \
    s0 = fmaf((pa).w, (c).w, s0); s1 = fmaf((pb).w, (c).w, s1); \
    s2 = fmaf((pc).w, (c).w, s2); s3 = fmaf((pd).w, (c).w, s3); } while (0)

// f64 sum-of-squares over one float4 (order-free: tie-invariant).
#define VQ_SQ(acc, q) do { \
    (acc) += (double)(q).x * (double)(q).x; \
    (acc) += (double)(q).y * (double)(q).y; \
    (acc) += (double)(q).z * (double)(q).z; \
    (acc) += (double)(q).w * (double)(q).w; } while (0)

// kernel1: cbsq[k] = fl32(sum_d f64(cb[k][d]^2)). Same numerics as the old
// in-block prologue (f64 accumulate, round once).
__global__ void vq_cbsq_kernel(const float* __restrict__ cb,
                               float* __restrict__ cbsq, int K)
{
    const int k = blockIdx.x * blockDim.x + threadIdx.x;
    if (k >= K) return;
    const float* c = cb + (size_t)k * VQ_D;
    double s = 0.0;
    #pragma unroll
    for (int d = 0; d < VQ_D; ++d) { double v = (double)c[d]; s += v * v; }
    cbsq[k] = (float)s;
}

template <bool USE_WS>
__global__ __launch_bounds__(256)
__attribute__((amdgpu_waves_per_eu(1, 1)))
void vq_argmin_kernel(
    const float* __restrict__ z_e,
    const float* __restrict__ cb,
    const float* __restrict__ cbsq_ws,   // valid iff USE_WS
    float* __restrict__ out,             // [N*D] z_q, then [N] indices (as float)
    int N, int K)
{
    __shared__ float s_cbsq[VQ_MAXK];    // used only if !USE_WS

    if (!USE_WS) {
        for (int k = threadIdx.x; k < K; k += blockDim.x) {
            const float* c = cb + (size_t)k * VQ_D;
            double s = 0.0;
            #pragma unroll
            for (int d = 0; d < VQ_D; ++d) { double v = (double)c[d]; s += v * v; }
            s_cbsq[k] = (float)s;
        }
        __syncthreads();
    }

    // Four rows per thread: nA = b*1024 + t, then +256 each. Clamp (not
    // return) so generic-N never diverges around the (optional) barrier.
    int nA = blockIdx.x * (4 * (int)blockDim.x) + threadIdx.x;
    const bool vA = (nA < N); if (!vA) nA = N - 1;
    int nB = nA + (int)blockDim.x;  const bool vB = (nB < N); if (!vB) nB = nA;
    int nC = nB + (int)blockDim.x;  const bool vC = (nC < N); if (!vC) nC = nA;
    int nD = nC + (int)blockDim.x;  const bool vD = (nD < N); if (!vD) nD = nA;

    // Four z rows in 64 NAMED float4 registers (NOT arrays — scratch hazard).
    const float4* zpa = (const float4*)(z_e + (size_t)nA * VQ_D);
    const float4* zpb = (const float4*)(z_e + (size_t)nB * VQ_D);
    const float4* zpc = (const float4*)(z_e + (size_t)nC * VQ_D);
    const float4* zpd = (const float4*)(z_e + (size_t)nD * VQ_D);
    float4 A0=zpa[0],A1=zpa[1],A2=zpa[2],A3=zpa[3],A4=zpa[4],A5=zpa[5],A6=zpa[6],A7=zpa[7];
    float4 A8=zpa[8],A9=zpa[9],A10=zpa[10],A11=zpa[11],A12=zpa[12],A13=zpa[13],A14=zpa[14],A15=zpa[15];
    float4 B0=zpb[0],B1=zpb[1],B2=zpb[2],B3=zpb[3],B4=zpb[4],B5=zpb[5],B6=zpb[6],B7=zpb[7];
    float4 B8=zpb[8],B9=zpb[9],B10=zpb[10],B11=zpb[11],B12=zpb[12],B13=zpb[13],B14=zpb[14],B15=zpb[15];
    float4 C0=zpc[0],C1=zpc[1],C2=zpc[2],C3=zpc[3],C4=zpc[4],C5=zpc[5],C6=zpc[6],C7=zpc[7];
    float4 C8=zpc[8],C9=zpc[9],C10=zpc[10],C11=zpc[11],C12=zpc[12],C13=zpc[13],C14=zpc[14],C15=zpc[15];
    float4 D0=zpd[0],D1=zpd[1],D2=zpd[2],D3=zpd[3],D4=zpd[4],D5=zpd[5],D6=zpd[6],D7=zpd[7];
    float4 D8=zpd[8],D9=zpd[9],D10=zpd[10],D11=zpd[11],D12=zpd[12],D13=zpd[13],D14=zpd[14],D15=zpd[15];

    // ||z||^2 in f64, rounded once (per row).
    double za=0.0, zb=0.0, zc=0.0, zd=0.0;
    VQ_SQ(za,A0); VQ_SQ(za,A1); VQ_SQ(za,A2); VQ_SQ(za,A3); VQ_SQ(za,A4); VQ_SQ(za,A5);
    VQ_SQ(za,A6); VQ_SQ(za,A7); VQ_SQ(za,A8); VQ_SQ(za,A9); VQ_SQ(za,A10);VQ_SQ(za,A11);
    VQ_SQ(za,A12);VQ_SQ(za,A13);VQ_SQ(za,A14);VQ_SQ(za,A15);
    VQ_SQ(zb,B0); VQ_SQ(zb,B1); VQ_SQ(zb,B2); VQ_SQ(zb,B3); VQ_SQ(zb,B4); VQ_SQ(zb,B5);
    VQ_SQ(zb,B6); VQ_SQ(zb,B7); VQ_SQ(zb,B8); VQ_SQ(zb,B9); VQ_SQ(zb,B10);VQ_SQ(zb,B11);
    VQ_SQ(zb,B12);VQ_SQ(zb,B13);VQ_SQ(zb,B14);VQ_SQ(zb,B15);
    VQ_SQ(zc,C0); VQ_SQ(zc,C1); VQ_SQ(zc,C2); VQ_SQ(zc,C3); VQ_SQ(zc,C4); VQ_SQ(zc,C5);
    VQ_SQ(zc,C6); VQ_SQ(zc,C7); VQ_SQ(zc,C8); VQ_SQ(zc,C9); VQ_SQ(zc,C10);VQ_SQ(zc,C11);
    VQ_SQ(zc,C12);VQ_SQ(zc,C13);VQ_SQ(zc,C14);VQ_SQ(zc,C15);
    VQ_SQ(zd,D0); VQ_SQ(zd,D1); VQ_SQ(zd,D2); VQ_SQ(zd,D3); VQ_SQ(zd,D4); VQ_SQ(zd,D5);
    VQ_SQ(zd,D6); VQ_SQ(zd,D7); VQ_SQ(zd,D8); VQ_SQ(zd,D9); VQ_SQ(zd,D10);VQ_SQ(zd,D11);
    VQ_SQ(zd,D12);VQ_SQ(zd,D13);VQ_SQ(zd,D14);VQ_SQ(zd,D15);
    const float zsqa = (float)za, zsqb = (float)zb, zsqc = (float)zc, zsqd = (float)zd;

    const float4* cbv = (const float4*)cb;   // plain pointer: stays VECTOR loads

    float bestA = 3.4e38f, bestB = 3.4e38f, bestC = 3.4e38f, bestD = 3.4e38f;
    int bkA = 0, bkB = 0, bkC = 0, bkD = 0;

    // Codebook row double-buffer in NAMED VGPR float4s. U = even k, W = odd k.
    float4 U0,U1,U2,U3,U4,U5,U6,U7,U8,U9,U10,U11,U12,U13,U14,U15; float cqU;
    float4 W0,W1,W2,W3,W4,W5,W6,W7,W8,W9,W10,W11,W12,W13,W14,W15; float cqW;

    // Prologue: U := row 0, W := row 1 (vmcnt-tracked; first use waits).
    {
        const float4* g0 = cbv;
        U0=g0[0];U1=g0[1];U2=g0[2];U3=g0[3];U4=g0[4];U5=g0[5];U6=g0[6];U7=g0[7];
        U8=g0[8];U9=g0[9];U10=g0[10];U11=g0[11];U12=g0[12];U13=g0[13];U14=g0[14];U15=g0[15];
        cqU = USE_WS ? cbsq_ws[0] : s_cbsq[0];
        const float4* g1 = cbv + 16;
        W0=g1[0];W1=g1[1];W2=g1[2];W3=g1[3];W4=g1[4];W5=g1[5];W6=g1[6];W7=g1[7];
        W8=g1[8];W9=g1[9];W10=g1[10];W11=g1[11];W12=g1[12];W13=g1[13];W14=g1[14];W15=g1[15];
        cqW = USE_WS ? cbsq_ws[1] : s_cbsq[1];
    }

    #pragma unroll 1
    for (int k = 0; k < K; k += 2) {
        // ---------------- row k (even) from U ----------------
        {
            float s0 = 0.f, s1 = 0.f, s2 = 0.f, s3 = 0.f;
            VQ_CH4(A0, B0, C0, D0, U0);   VQ_CH4(A1, B1, C1, D1, U1);
            VQ_CH4(A2, B2, C2, D2, U2);   VQ_CH4(A3, B3, C3, D3, U3);
            VQ_CH4(A4, B4, C4, D4, U4);   VQ_CH4(A5, B5, C5, D5, U5);
            VQ_CH4(A6, B6, C6, D6, U6);   VQ_CH4(A7, B7, C7, D7, U7);
            VQ_CH4(A8, B8, C8, D8, U8);   VQ_CH4(A9, B9, C9, D9, U9);
            VQ_CH4(A10,B10,C10,D10,U10);  VQ_CH4(A11,B11,C11,D11,U11);
            VQ_CH4(A12,B12,C12,D12,U12);  VQ_CH4(A13,B13,C13,D13,U13);
            VQ_CH4(A14,B14,C14,D14,U14);  VQ_CH4(A15,B15,C15,D15,U15);
            const float dA = (zsqa - 2.0f * s0) + cqU;   // fp32 rounds, as ref
            const float dB = (zsqb - 2.0f * s1) + cqU;
            const float dC = (zsqc - 2.0f * s2) + cqU;
            const float dD = (zsqd - 2.0f * s3) + cqU;
            if (dA < bestA) { bestA = dA; bkA = k; }     // strict <: lowest k
            if (dB < bestB) { bestB = dB; bkB = k; }
            if (dC < bestC) { bestC = dC; bkC = k; }
            if (dD < bestD) { bestD = dD; bkD = k; }
            // Reissue U := row k+2 (clamped; last-iter refetch lands unused).
            int nk = k + 2; if (nk >= K) nk = K - 2;
            const float4* gp = cbv + ((size_t)nk << 4);
            U0=gp[0];U1=gp[1];U2=gp[2];U3=gp[3];U4=gp[4];U5=gp[5];U6=gp[6];U7=gp[7];
            U8=gp[8];U9=gp[9];U10=gp[10];U11=gp[11];U12=gp[12];U13=gp[13];U14=gp[14];U15=gp[15];
            cqU = USE_WS ? cbsq_ws[nk] : s_cbsq[nk];
        }
        // ---------------- row k+1 (odd) from W ---------------
        {
            float s0 = 0.f, s1 = 0.f, s2 = 0.f, s3 = 0.f;
            VQ_CH4(A0, B0, C0, D0, W0);   VQ_CH4(A1, B1, C1, D1, W1);
            VQ_CH4(A2, B2, C2, D2, W2);   VQ_CH4(A3, B3, C3, D3, W3);
            VQ_CH4(A4, B4, C4, D4, W4);   VQ_CH4(A5, B5, C5, D5, W5);
            VQ_CH4(A6, B6, C6, D6, W6);   VQ_CH4(A7, B7, C7, D7, W7);
            VQ_CH4(A8, B8, C8, D8, W8);   VQ_CH4(A9, B9, C9, D9, W9);
            VQ_CH4(A10,B10,C10,D10,W10);  VQ_CH4(A11,B11,C11,D11,W11);
            VQ_CH4(A12,B12,C12,D12,W12);  VQ_CH4(A13,B13,C13,D13,W13);
            VQ_CH4(A14,B14,C14,D14,W14);  VQ_CH4(A15,B15,C15,D15,W15);
            const float dA = (zsqa - 2.0f * s0) + cqW;
            const float dB = (zsqb - 2.0f * s1) + cqW;
            const float dC = (zsqc - 2.0f * s2) + cqW;
            const float dD = (zsqd - 2.0f * s3) + cqW;
            if (dA < bestA) { bestA = dA; bkA = k + 1; }
            if (dB < bestB) { bestB = dB; bkB = k + 1; }
            if (dC < bestC) { bestC = dC; bkC = k + 1; }
            if (dD < bestD) { bestD = dD; bkD = k + 1; }
            // Reissue W := row k+3 (clamped).
            int nk = k + 3; if (nk >= K) nk = K - 1;
            const float4* gp = cbv + ((size_t)nk << 4);
            W0=gp[0];W1=gp[1];W2=gp[2];W3=gp[3];W4=gp[4];W5=gp[5];W6=gp[6];W7=gp[7];
            W8=gp[8];W9=gp[9];W10=gp[10];W11=gp[11];W12=gp[12];W13=gp[13];W14=gp[14];W15=gp[15];
            cqW = USE_WS ? cbsq_ws[nk] : s_cbsq[nk];
        }
    }

    // z_q gathers (divergent index -> per-lane VMEM; codebook L2-resident).
    if (vA) {
        const float4* g = (const float4*)(cb + (size_t)bkA * VQ_D);
        float4* o = (float4*)(out + (size_t)nA * VQ_D);
        #pragma unroll
        for (int i = 0; i < VQ_D / 4; ++i) o[i] = g[i];
        out[(size_t)N * VQ_D + nA] = (float)bkA;
    }
    if (vB) {
        const float4* g = (const float4*)(cb + (size_t)bkB * VQ_D);
        float4* o = (float4*)(out + (size_t)nB * VQ_D);
        #pragma unroll
        for (int i = 0; i < VQ_D / 4; ++i) o[i] = g[i];
        out[(size_t)N * VQ_D + nB] = (float)bkB;
    }
    if (vC) {
        const float4* g = (const float4*)(cb + (size_t)bkC * VQ_D);
        float4* o = (float4*)(out + (size_t)nC * VQ_D);
        #pragma unroll
        for (int i = 0; i < VQ_D / 4; ++i) o[i] = g[i];
        out[(size_t)N * VQ_D + nC] = (float)bkC;
    }
    if (vD) {
        const float4* g = (const float4*)(cb + (size_t)bkD * VQ_D);
        float4* o = (float4*)(out + (size_t)nD * VQ_D);
        #pragma unroll
        for (int i = 0; i < VQ_D / 4; ++i) o[i] = g[i];
        out[(size_t)N * VQ_D + nD] = (float)bkD;
    }
}

extern "C" void kernel_launch(void* const* d_in, const int* in_sizes, int n_in,
                              void* d_out, int out_size, void* d_ws, size_t ws_size,
                              hipStream_t stream) {
    const float* z_e = (const float*)d_in[0];
    const float* cb  = (const float*)d_in[1];
    float* out = (float*)d_out;

    const int N = in_sizes[0] / VQ_D;
    const int K = in_sizes[1] / VQ_D;

    const int block = 256;
    const int rows_per_block = 4 * block;
    const int grid = (N + rows_per_block - 1) / rows_per_block;

    const bool use_ws = (d_ws != nullptr) && (ws_size >= (size_t)K * sizeof(float));
    if (use_ws) {
        float* cbsq = (float*)d_ws;
        vq_cbsq_kernel<<<(K + 255) / 256, 256, 0, stream>>>(cb, cbsq, K);
        vq_argmin_kernel<true><<<grid, block, 0, stream>>>(z_e, cb, cbsq, out, N, K);
    } else {
        vq_argmin_kernel<false><<<grid, block, 0, stream>>>(z_e, cb, nullptr, out, N, K);
    }
}

// Round 11
// 584.222 us; speedup vs baseline: 4.2866x; 4.2866x over previous
//
#include <hip/hip_runtime.h>

// VQ nearest-codebook: N=262144 rows x D=64, K=1024 codes.
// Numerics contract (bit-exact vs np f32 reference, verified in prior session):
//   dist_k = fl32( fl32(zsq - 2*dot_k) + cbsq_k ), argmin -> lowest index wins.
//   dot_k MUST be one sequential fmaf chain d=0..63 per row. DO NOT re-associate.
//   zsq/cbsq: f64-accumulate then round once.
//
// R14 change: R12 structure + half-row loads as f32x16 -> s_load_dwordx16.
//   Diagnosis: R13 (R=4) hit the v0-v255 addressing wall (non-MFMA code cannot
//   use >256 VGPRs) -> spill, 2475us, dead. Plateau theory revised: per k-step
//   per SIMD = 512 cyc FMA issue, wall 1220 -> gap 708 cyc. ONE scalar pipe
//   per CU serves all 4 SIMDs: if the f4 reads didn't merge, 8 waves x 17
//   s_loads = 136 scalar ops/k/CU x ~5cyc ~ 680 cyc = the gap. So: load each
//   32-float half-row as TWO ext_vector(16) float AS4 loads = s_load_dwordx16.
//   17 -> 5 scalar ops per wave per k (40/CU ~ 200 cyc < 512 FMA) -> scalar
//   pipe off the critical path. R5 died hand-allocating these tuples in asm;
//   compiler-managed selection/allocation (proven for f4) owns it here.
//   Null outcome (dur ~520 unchanged) = loads were already merged -> latency
//   theory next. Gates: SGPR ~104-120, VGPR ~124, WRITE ~68MB.
//   NO per-thread arrays anywhere (scratch hazard) -- all named values.

#define VQ_D 64
#define VQ_MAXK 1024

typedef __attribute__((ext_vector_type(16))) float f16v;
typedef const __attribute__((address_space(4))) f16v* cb16c_t;
typedef const __attribute__((address_space(4))) float* fc_t;

// Two-row sequential fused-FMA chain step over 4 consecutive c elements taken
// from an f32x16 at compile-time base j (ascending d within each row's chain;
// chains independent -> ILP without reassociation). cv is SGPR-resident.
#define VQ_CH2V(qa, qb, cv, j) do { \
    s0 = fmaf((qa).x, (cv)[(j)+0], s0); s1 = fmaf((qb).x, (cv)[(j)+0], s1); \
    s0 = fmaf((qa).y, (cv)[(j)+1], s0); s1 = fmaf((qb).y, (cv)[(j)+1], s1); \
    s0 = fmaf((qa).z, (cv)[(j)+2], s0); s1 = fmaf((qb).z, (cv)[(j)+2], s1); \
    s0 = fmaf((qa).w, (cv)[(j)+3], s0); s1 = fmaf((qb).w, (cv)[(j)+3], s1); } while (0)

// f64 sum-of-squares over one float4 (order-free: tie-invariant).
#define VQ_SQ(acc, q) do { \
    (acc) += (double)(q).x * (double)(q).x; \
    (acc) += (double)(q).y * (double)(q).y; \
    (acc) += (double)(q).z * (double)(q).z; \
    (acc) += (double)(q).w * (double)(q).w; } while (0)

#define SBAR() __builtin_amdgcn_sched_barrier(0)

// kernel1: cbsq[k] = fl32(sum_d f64(cb[k][d]^2)). Same numerics as the old
// in-block prologue (f64 accumulate, round once).
__global__ void vq_cbsq_kernel(const float* __restrict__ cb,
                               float* __restrict__ cbsq, int K)
{
    const int k = blockIdx.x * blockDim.x + threadIdx.x;
    if (k >= K) return;
    const float* c = cb + (size_t)k * VQ_D;
    double s = 0.0;
    #pragma unroll
    for (int d = 0; d < VQ_D; ++d) { double v = (double)c[d]; s += v * v; }
    cbsq[k] = (float)s;
}

template <bool USE_WS>
__global__ __launch_bounds__(256)
__attribute__((amdgpu_waves_per_eu(2, 2)))
void vq_argmin_kernel(
    const float* __restrict__ z_e,
    const float* __restrict__ cb,
    const float* __restrict__ cbsq_ws,   // valid iff USE_WS
    float* __restrict__ out,             // [N*D] z_q, then [N] indices (as float)
    int N, int K)
{
    __shared__ float s_cbsq[VQ_MAXK];    // used only if !USE_WS

    if (!USE_WS) {
        for (int k = threadIdx.x; k < K; k += blockDim.x) {
            const float* c = cb + (size_t)k * VQ_D;
            double s = 0.0;
            #pragma unroll
            for (int d = 0; d < VQ_D; ++d) { double v = (double)c[d]; s += v * v; }
            s_cbsq[k] = (float)s;
        }
        __syncthreads();
    }

    // Two rows per thread: n0 = b*512 + t, n1 = n0 + 256.
    int n0 = blockIdx.x * (2 * (int)blockDim.x) + threadIdx.x;
    if (n0 >= N) return;                 // after the (optional) barrier: legal
    int n1 = n0 + (int)blockDim.x;
    if (n1 >= N) n1 = n0;                // harmless duplicate; never hit here

    // Both z rows in 32 NAMED float4 registers (NOT arrays — scratch hazard).
    const float4* zp0 = (const float4*)(z_e + (size_t)n0 * VQ_D);
    const float4* zp1 = (const float4*)(z_e + (size_t)n1 * VQ_D);
    float4 a0  = zp0[0],  a1  = zp0[1],  a2  = zp0[2],  a3  = zp0[3];
    float4 a4  = zp0[4],  a5  = zp0[5],  a6  = zp0[6],  a7  = zp0[7];
    float4 a8  = zp0[8],  a9  = zp0[9],  a10 = zp0[10], a11 = zp0[11];
    float4 a12 = zp0[12], a13 = zp0[13], a14 = zp0[14], a15 = zp0[15];
    float4 b0  = zp1[0],  b1  = zp1[1],  b2  = zp1[2],  b3  = zp1[3];
    float4 b4  = zp1[4],  b5  = zp1[5],  b6  = zp1[6],  b7  = zp1[7];
    float4 b8  = zp1[8],  b9  = zp1[9],  b10 = zp1[10], b11 = zp1[11];
    float4 b12 = zp1[12], b13 = zp1[13], b14 = zp1[14], b15 = zp1[15];

    // ||z||^2 in f64, rounded once (per row).
    double zs0 = 0.0, zs1 = 0.0;
    VQ_SQ(zs0, a0);  VQ_SQ(zs0, a1);  VQ_SQ(zs0, a2);  VQ_SQ(zs0, a3);
    VQ_SQ(zs0, a4);  VQ_SQ(zs0, a5);  VQ_SQ(zs0, a6);  VQ_SQ(zs0, a7);
    VQ_SQ(zs0, a8);  VQ_SQ(zs0, a9);  VQ_SQ(zs0, a10); VQ_SQ(zs0, a11);
    VQ_SQ(zs0, a12); VQ_SQ(zs0, a13); VQ_SQ(zs0, a14); VQ_SQ(zs0, a15);
    VQ_SQ(zs1, b0);  VQ_SQ(zs1, b1);  VQ_SQ(zs1, b2);  VQ_SQ(zs1, b3);
    VQ_SQ(zs1, b4);  VQ_SQ(zs1, b5);  VQ_SQ(zs1, b6);  VQ_SQ(zs1, b7);
    VQ_SQ(zs1, b8);  VQ_SQ(zs1, b9);  VQ_SQ(zs1, b10); VQ_SQ(zs1, b11);
    VQ_SQ(zs1, b12); VQ_SQ(zs1, b13); VQ_SQ(zs1, b14); VQ_SQ(zs1, b15);
    const float zsq0 = (float)zs0;
    const float zsq1 = (float)zs1;

    // Constant-AS f32x16 view -> uniform 64B loads become s_load_dwordx16.
    // 4 chunks per 256B row: [4k]=d0..15, [4k+1]=d16..31, [4k+2]=d32..47,
    // [4k+3]=d48..63.
    cb16c_t cbc = (cb16c_t)(unsigned long long)cb;
    fc_t    sqc = (fc_t)(unsigned long long)cbsq_ws;

    float best0 = 3.4e38f, best1 = 3.4e38f;
    int bk0 = 0, bk1 = 0;

    // Half-row ping-pong buffers (SGPR f32x16 pairs). X = d0..31, Y = d32..63.
    f16v XA, XB, YA, YB;
    float cq;

    // Prologue: issue A(0) into X. (One-time short-distance wait at k=0.)
    XA = cbc[0]; XB = cbc[1];

    #pragma unroll 1
    for (int k = 0; k < K; ++k) {
        const int kb = k << 2;
        float s0 = 0.f, s1 = 0.f;

        // First X use: lgkmcnt(0) lands HERE, draining X issued mid-B-block of
        // the previous iteration.
        VQ_CH2V(a0, b0, XA, 0);
        SBAR();
        // Issue box: B(k) -> Y (2 x dwordx16), plus cbsq(k). Boxed so the
        // scheduler can neither hoist these above the X-wait nor sink them.
        YA = cbc[kb + 2]; YB = cbc[kb + 3];
        cq = USE_WS ? sqc[k] : s_cbsq[k];
        SBAR();
        // Rest of A-half (d4..31), sequential ascending d.
        VQ_CH2V(a1, b1, XA, 4);  VQ_CH2V(a2, b2, XA, 8);  VQ_CH2V(a3, b3, XA, 12);
        VQ_CH2V(a4, b4, XB, 0);  VQ_CH2V(a5, b5, XB, 4);  VQ_CH2V(a6, b6, XB, 8);
        VQ_CH2V(a7, b7, XB, 12);

        // First Y use: lgkmcnt(0) lands HERE, draining Y+cq.
        VQ_CH2V(a8, b8, YA, 0);
        SBAR();
        // Issue box: A(k+1) -> X (clamped last iter; 128B reload, harmless).
        {
            int nk = k + 1; if (nk >= K) nk = K - 1;
            const int nb = nk << 2;
            XA = cbc[nb + 0]; XB = cbc[nb + 1];
        }
        SBAR();
        // Rest of B-half (d36..63), sequential ascending d.
        VQ_CH2V(a9,  b9,  YA, 4);  VQ_CH2V(a10, b10, YA, 8);  VQ_CH2V(a11, b11, YA, 12);
        VQ_CH2V(a12, b12, YB, 0);  VQ_CH2V(a13, b13, YB, 4);  VQ_CH2V(a14, b14, YB, 8);
        VQ_CH2V(a15, b15, YB, 12);

        // cq completed at the Y-wait; no further lgkm wait needed here.
        const float u0    = zsq0 - 2.0f * s0;   // 2*s exact; one fp32 round
        const float dist0 = u0 + cq;            // fp32 round, as reference
        const float u1    = zsq1 - 2.0f * s1;
        const float dist1 = u1 + cq;
        if (dist0 < best0) { best0 = dist0; bk0 = k; }  // strict <: lowest k
        if (dist1 < best1) { best1 = dist1; bk1 = k; }
    }

    // z_q gathers (divergent index -> per-lane VMEM; codebook L2-resident).
    {
        const float4* cq0 = (const float4*)(cb + (size_t)bk0 * VQ_D);
        float4* oq0 = (float4*)(out + (size_t)n0 * VQ_D);
        #pragma unroll
        for (int i = 0; i < VQ_D / 4; ++i) oq0[i] = cq0[i];
        const float4* cq1 = (const float4*)(cb + (size_t)bk1 * VQ_D);
        float4* oq1 = (float4*)(out + (size_t)n1 * VQ_D);
        #pragma unroll
        for (int i = 0; i < VQ_D / 4; ++i) oq1[i] = cq1[i];
    }

    // Indices as float (exact for k < 2^24).
    out[(size_t)N * VQ_D + n0] = (float)bk0;
    out[(size_t)N * VQ_D + n1] = (float)bk1;
}

extern "C" void kernel_launch(void* const* d_in, const int* in_sizes, int n_in,
                              void* d_out, int out_size, void* d_ws, size_t ws_size,
                              hipStream_t stream) {
    const float* z_e = (const float*)d_in[0];
    const float* cb  = (const float*)d_in[1];
    float* out = (float*)d_out;

    const int N = in_sizes[0] / VQ_D;
    const int K = in_sizes[1] / VQ_D;

    const int block = 256;
    const int rows_per_block = 2 * block;
    const int grid = (N + rows_per_block - 1) / rows_per_block;

    const bool use_ws = (d_ws != nullptr) && (ws_size >= (size_t)K * sizeof(float));
    if (use_ws) {
        float* cbsq = (float*)d_ws;
        vq_cbsq_kernel<<<(K + 255) / 256, 256, 0, stream>>>(cb, cbsq, K);
        vq_argmin_kernel<true><<<grid, block, 0, stream>>>(z_e, cb, cbsq, out, N, K);
    } else {
        vq_argmin_kernel<false><<<grid, block, 0, stream>>>(z_e, cb, nullptr, out, N, K);
    }
}